// Round 1
// baseline (714.688 us; speedup 1.0000x reference)
//
#include <hip/hip_runtime.h>
#include <math.h>

#define NPTS   8192
#define BATCH  4
#define KNN    20
#define NKTOT  (NPTS*KNN)        // 163840 spatial positions per batch
#define EPS    1e-5f
#define TILE   2048              // knn point tile (32KB LDS as float4)
#define QPW    8                 // queries per wave in knn

__device__ __forceinline__ float elu(float x) { return x > 0.0f ? x : expm1f(x); }

// monotone float <-> unsigned encoding for atomic max/min on floats
__device__ __forceinline__ unsigned fenc(float f) {
    unsigned b = __float_as_uint(f);
    return b ^ ((unsigned)(((int)b) >> 31) | 0x80000000u);
}
__device__ __forceinline__ float fdec(unsigned u) {
    unsigned b = (u & 0x80000000u) ? (u ^ 0x80000000u) : ~u;
    return __uint_as_float(b);
}

// ---------------------------------------------------------------------------
// K1: KNN. One wave per query; distributed sorted top-20 in lanes 0..19.
// grid: 512 blocks x 512 threads (128 blocks/batch, 64 queries/block)
// ---------------------------------------------------------------------------
__global__ __launch_bounds__(512) void knn_kernel(const float* __restrict__ points,
                                                  int* __restrict__ idx_out)
{
    __shared__ __align__(16) float4 pts[TILE];
    const int tid  = threadIdx.x;
    const int lane = tid & 63;
    const int wv   = tid >> 6;            // 0..7
    const int b    = blockIdx.x >> 7;     // 128 blocks per batch
    const int q0   = (blockIdx.x & 127) * 64;
    const float* px = points + b * 3 * NPTS;

    float ld[QPW]; int li[QPW];
#pragma unroll
    for (int q = 0; q < QPW; ++q) { ld[q] = INFINITY; li[q] = -1; }

    for (int tile = 0; tile < NPTS / TILE; ++tile) {
        __syncthreads();
        for (int i = tid; i < TILE; i += 512) {
            int j = tile * TILE + i;
            float x = px[j], y = px[NPTS + j], z = px[2 * NPTS + j];
            pts[i] = make_float4(x, y, z, x * x + y * y + z * z);
        }
        __syncthreads();
        for (int qq = 0; qq < QPW; ++qq) {
            const int qi = q0 + wv * QPW + qq;
            const float qx = px[qi], qy = px[NPTS + qi], qz = px[2 * NPTS + qi];
            const float qsq = qx * qx + qy * qy + qz * qz;
            float myd = ld[qq]; int myi = li[qq];
            float tau = __shfl(myd, 19);
            for (int s = 0; s < TILE / 64; ++s) {
                const int jj = s * 64 + lane;
                float4 p = pts[jj];
                float dot = qx * p.x + qy * p.y + qz * p.z;
                float d = (qsq + p.w) - 2.0f * dot;     // same formula/order as ref
                int jidx = tile * TILE + jj;
                unsigned long long bal = __ballot(d < tau);
                while (bal) {
                    int src = __ffsll(bal) - 1;
                    bal &= bal - 1;
                    float vd = __shfl(d, src);
                    int   vi = __shfl(jidx, src);
                    if (vd < tau) {                      // re-check against updated tau
                        int   sh = (myd > vd) ? 1 : 0;   // strict: equal dists keep earlier idx first
                        float pd = __shfl_up(myd, 1);
                        int   pi = __shfl_up(myi, 1);
                        int   ps = __shfl_up(sh, 1);
                        bool pshift = (lane > 0) && (ps != 0);
                        float nd = sh ? (pshift ? pd : vd) : myd;
                        int   ni = sh ? (pshift ? pi : vi) : myi;
                        myd = nd; myi = ni;
                        tau = __shfl(myd, 19);
                    }
                }
            }
            ld[qq] = myd; li[qq] = myi;
        }
    }
#pragma unroll
    for (int qq = 0; qq < QPW; ++qq) {
        const int qi = q0 + wv * QPW + qq;
        if (lane < KNN) idx_out[(b * NPTS + qi) * KNN + lane] = li[qq];
    }
}

// ---------------------------------------------------------------------------
// K2: accumulate per-batch x0 moments: 6 sums + 21 upper-tri products.
// grid: 2560 x 256  (one thread per (b,n,k) position)
// ---------------------------------------------------------------------------
__global__ __launch_bounds__(256) void moments_x_kernel(const float* __restrict__ points,
                                                        const int* __restrict__ idx,
                                                        float* __restrict__ sums1p)
{
    const int t = blockIdx.x * 256 + threadIdx.x;
    const int b = blockIdx.x / 640;                 // 640 blocks per batch
    const int r = t - b * NKTOT;
    const int n = r / KNN;
    const float* px = points + b * 3 * NPTS;
    const int j = idx[t];
    float cx = px[n], cy = px[NPTS + n], cz = px[2 * NPTS + n];
    float v[27];
    v[0] = cx; v[1] = cy; v[2] = cz;
    v[3] = px[j] - cx; v[4] = px[NPTS + j] - cy; v[5] = px[2 * NPTS + j] - cz;
    int p = 6;
#pragma unroll
    for (int d = 0; d < 6; ++d)
#pragma unroll
        for (int e = d; e < 6; ++e) v[p++] = v[d] * v[e];
#pragma unroll
    for (int i = 0; i < 27; ++i)
        for (int o = 32; o > 0; o >>= 1) v[i] += __shfl_xor(v[i], o);

    __shared__ float red[4][27];
    const int lane = threadIdx.x & 63, w = threadIdx.x >> 6;
    if (lane == 0)
#pragma unroll
        for (int i = 0; i < 27; ++i) red[w][i] = v[i];
    __syncthreads();
    if (threadIdx.x < 27) {
        float acc = red[0][threadIdx.x] + red[1][threadIdx.x] + red[2][threadIdx.x] + red[3][threadIdx.x];
        int slot = blockIdx.x & 63;
        atomicAdd(&sums1p[(slot * BATCH + b) * 27 + threadIdx.x], acc);
    }
}

// ---------------------------------------------------------------------------
// K3: finalize GN1 stats -> per-channel affine s1,t1.  1 block x 128 threads
// ---------------------------------------------------------------------------
__global__ void finalize1_kernel(const float* __restrict__ sums1p,
                                 const float* __restrict__ w1, const float* __restrict__ b1,
                                 const float* __restrict__ g1, const float* __restrict__ beta1,
                                 float* __restrict__ s1, float* __restrict__ t1)
{
    __shared__ float S[BATCH][27];
    const int t = threadIdx.x;
    if (t < 108) {
        int b = t / 27, i = t % 27;
        float acc = 0.f;
        for (int s = 0; s < 64; ++s) acc += sums1p[(s * BATCH + b) * 27 + i];
        S[b][i] = acc;
    }
    __syncthreads();
    const int b = t >> 5, c = t & 31;
    const float invS = 1.0f / (float)NKTOT;
    float Ex[6], M[6][6];
#pragma unroll
    for (int d = 0; d < 6; ++d) Ex[d] = S[b][d] * invS;
    int p = 6;
#pragma unroll
    for (int d = 0; d < 6; ++d)
#pragma unroll
        for (int e = d; e < 6; ++e) { float v = S[b][p++] * invS; M[d][e] = v; M[e][d] = v; }
    const int g = c >> 2;
    float msum = 0.f, qsum = 0.f;
    for (int cc = g * 4; cc < g * 4 + 4; ++cc) {
        float w[6];
#pragma unroll
        for (int d = 0; d < 6; ++d) w[d] = w1[cc * 6 + d];
        float dotEx = 0.f;
#pragma unroll
        for (int d = 0; d < 6; ++d) dotEx += w[d] * Ex[d];
        float Ey = dotEx + b1[cc];
        float Ey2 = 0.f;
#pragma unroll
        for (int d = 0; d < 6; ++d)
#pragma unroll
            for (int e = 0; e < 6; ++e) Ey2 += w[d] * w[e] * M[d][e];
        Ey2 += 2.0f * b1[cc] * dotEx + b1[cc] * b1[cc];
        msum += Ey; qsum += Ey2;
    }
    float m = msum * 0.25f;
    float var = qsum * 0.25f - m * m;
    float inv = rsqrtf(var + EPS);
    s1[b * 32 + c] = g1[c] * inv;
    t1[b * 32 + c] = g1[c] * inv * (b1[c] - m) + beta1[c];
}

// ---------------------------------------------------------------------------
// K4: fused main pass: z1 tile (LDS) -> y2 GEMM (reg-tiled) -> GN2 stats +
// per-(b,c,k) max/min over n via encoded atomics.
// grid: 4*20*128 = 10240 blocks x 256 threads. Block covers 64 n's at fixed k.
// ---------------------------------------------------------------------------
__global__ __launch_bounds__(256) void fused_main_kernel(
    const float* __restrict__ points, const int* __restrict__ idxb,
    const float* __restrict__ w1, const float* __restrict__ s1a, const float* __restrict__ t1a,
    const float* __restrict__ w2, const float* __restrict__ b2,
    float* __restrict__ sums2p, unsigned int* __restrict__ maxenc, unsigned int* __restrict__ minenc)
{
    __shared__ __align__(16) float w2t[32 * 68];   // W2^T, padded stride 68 (16B aligned rows)
    __shared__ __align__(16) float z1s[32 * 64];
    __shared__ float w1s[192];
    __shared__ float s1s[32], t1s[32], b2s[64];

    const int t = threadIdx.x;
    const int blk = blockIdx.x;
    const int nchunk = blk & 127;
    const int k = (blk >> 7) % 20;
    const int b = blk / (128 * 20);

    for (int i = t; i < 2048; i += 256) { int c = i >> 5, kk = i & 31; w2t[kk * 68 + c] = w2[i]; }
    if (t < 192) w1s[t] = w1[t];
    if (t < 32) { s1s[t] = s1a[b * 32 + t]; t1s[t] = t1a[b * 32 + t]; }
    if (t < 64) b2s[t] = b2[t];

    const int p = t & 63;
    const int cg = t >> 6;
    const int n = nchunk * 64 + p;
    const float* px = points + b * 3 * NPTS;
    const int j = idxb[(b * NPTS + n) * KNN + k];
    const float cx = px[n], cy = px[NPTS + n], cz = px[2 * NPTS + n];
    float x0[6];
    x0[0] = cx; x0[1] = cy; x0[2] = cz;
    x0[3] = px[j] - cx; x0[4] = px[NPTS + j] - cy; x0[5] = px[2 * NPTS + j] - cz;
    __syncthreads();
#pragma unroll
    for (int jj = 0; jj < 8; ++jj) {
        int c = cg * 8 + jj;
        float acc = 0.f;
#pragma unroll
        for (int d = 0; d < 6; ++d) acc += w1s[c * 6 + d] * x0[d];
        z1s[c * 64 + p] = elu(s1s[c] * acc + t1s[c]);
    }
    __syncthreads();

    const int pos0 = (t & 15) * 4;
    const int c0 = (t >> 4) * 4;
    float acc[4][4];
#pragma unroll
    for (int ci = 0; ci < 4; ++ci) {
        float bb = b2s[c0 + ci];
#pragma unroll
        for (int pj = 0; pj < 4; ++pj) acc[ci][pj] = bb;
    }
#pragma unroll
    for (int kk = 0; kk < 32; ++kk) {
        float4 av = *(const float4*)&w2t[kk * 68 + c0];
        float4 bv = *(const float4*)&z1s[kk * 64 + pos0];
        float avv[4] = { av.x, av.y, av.z, av.w };
        float bvv[4] = { bv.x, bv.y, bv.z, bv.w };
#pragma unroll
        for (int ci = 0; ci < 4; ++ci)
#pragma unroll
            for (int pj = 0; pj < 4; ++pj) acc[ci][pj] += avv[ci] * bvv[pj];
    }

    float ssum = 0.f, ssq = 0.f;
    float mx[4], mn[4];
#pragma unroll
    for (int ci = 0; ci < 4; ++ci) {
        float cmx = -INFINITY, cmn = INFINITY;
#pragma unroll
        for (int pj = 0; pj < 4; ++pj) {
            float v = acc[ci][pj];
            ssum += v; ssq += v * v;
            cmx = fmaxf(cmx, v); cmn = fminf(cmn, v);
        }
        mx[ci] = cmx; mn[ci] = cmn;
    }
#pragma unroll
    for (int o = 1; o < 16; o <<= 1) {
        ssum += __shfl_xor(ssum, o);
        ssq  += __shfl_xor(ssq, o);
#pragma unroll
        for (int ci = 0; ci < 4; ++ci) {
            mx[ci] = fmaxf(mx[ci], __shfl_xor(mx[ci], o));
            mn[ci] = fminf(mn[ci], __shfl_xor(mn[ci], o));
        }
    }
    if ((t & 15) == 0) {
        int g = c0 >> 3, slot = blk & 63;
        atomicAdd(&sums2p[((slot * BATCH + b) * 8 + g) * 2 + 0], ssum);
        atomicAdd(&sums2p[((slot * BATCH + b) * 8 + g) * 2 + 1], ssq);
#pragma unroll
        for (int ci = 0; ci < 4; ++ci) {
            int c = c0 + ci;
            atomicMax(&maxenc[(b * 64 + c) * KNN + k], fenc(mx[ci]));
            atomicMin(&minenc[(b * 64 + c) * KNN + k], fenc(mn[ci]));
        }
    }
}

// ---------------------------------------------------------------------------
// K5: build m1[b,c,k] = ELU(GN2-affine applied to max-or-min over n of y2)
// grid: 20 x 256 (5120 threads)
// ---------------------------------------------------------------------------
__global__ void build_m1_kernel(const float* __restrict__ sums2p,
                                const unsigned int* __restrict__ maxenc,
                                const unsigned int* __restrict__ minenc,
                                const float* __restrict__ gamma, const float* __restrict__ beta,
                                float* __restrict__ m1)
{
    const int t = blockIdx.x * 256 + threadIdx.x;   // (b*64+c)*20+k
    const int b = t / 1280;
    const int r = t - b * 1280;
    const int c = r / 20;
    const int g = c >> 3;
    float s = 0.f, q = 0.f;
    for (int sl = 0; sl < 64; ++sl) {
        s += sums2p[((sl * BATCH + b) * 8 + g) * 2 + 0];
        q += sums2p[((sl * BATCH + b) * 8 + g) * 2 + 1];
    }
    const float cnt = 8.0f * (float)NKTOT;
    float m = s / cnt;
    float var = q / cnt - m * m;
    float inv = rsqrtf(var + EPS);
    float sc = gamma[c] * inv;
    float tt = beta[c] - sc * m;
    float y = (sc >= 0.f) ? fdec(maxenc[t]) : fdec(minenc[t]);
    m1[t] = elu(sc * y + tt);
}

// ---------------------------------------------------------------------------
// K6/K8: pointwise conv (CIN -> COUT over K=20) + raw output + GN stat partials
// ---------------------------------------------------------------------------
template <int CIN, int SLOTS>
__global__ void p2_gemm_kernel(const float* __restrict__ zin, const float* __restrict__ w,
                               const float* __restrict__ bias, float* __restrict__ yout,
                               float* __restrict__ sumsp, int chans_per_group)
{
    const int t = blockIdx.x * 256 + threadIdx.x;
    const int per_b = (gridDim.x * 256) / BATCH;
    const int b = t / per_b;
    const int r = t - b * per_b;
    const int o = r / 20;
    const int k = r - o * 20;
    const float* zb = zin + b * CIN * 20;
    const float* wrow = w + o * CIN;
    float acc = bias[o];
    for (int c = 0; c < CIN; c += 4) {
        float4 wv = *(const float4*)&wrow[c];
        acc += wv.x * zb[(c + 0) * 20 + k] + wv.y * zb[(c + 1) * 20 + k]
             + wv.z * zb[(c + 2) * 20 + k] + wv.w * zb[(c + 3) * 20 + k];
    }
    yout[t] = acc;

    __shared__ float ls[16];
    if (threadIdx.x < 16) ls[threadIdx.x] = 0.f;
    __syncthreads();
    const int g = o / chans_per_group;
    atomicAdd(&ls[g * 2 + 0], acc);
    atomicAdd(&ls[g * 2 + 1], acc * acc);
    __syncthreads();
    if (threadIdx.x < 16) {
        int slot = blockIdx.x & (SLOTS - 1);
        atomicAdd(&sumsp[(slot * BATCH + b) * 16 + threadIdx.x], ls[threadIdx.x]);
    }
}

// K7/K9: apply GN affine + ELU using partial sums
template <int SLOTS>
__global__ void p2_finalize_kernel(const float* __restrict__ y, const float* __restrict__ sumsp,
                                   const float* __restrict__ gamma, const float* __restrict__ beta,
                                   float* __restrict__ z, int chans_per_group, float cnt)
{
    const int t = blockIdx.x * 256 + threadIdx.x;
    const int per_b = (gridDim.x * 256) / BATCH;
    const int b = t / per_b;
    const int r = t - b * per_b;
    const int o = r / 20;
    const int g = o / chans_per_group;
    float s = 0.f, q = 0.f;
    for (int sl = 0; sl < SLOTS; ++sl) {
        s += sumsp[(sl * BATCH + b) * 16 + g * 2 + 0];
        q += sumsp[(sl * BATCH + b) * 16 + g * 2 + 1];
    }
    float m = s / cnt;
    float var = q / cnt - m * m;
    float inv = rsqrtf(var + EPS);
    float v = gamma[o] * inv * (y[t] - m) + beta[o];
    z[t] = elu(v);
}

// ---------------------------------------------------------------------------
extern "C" void kernel_launch(void* const* d_in, const int* in_sizes, int n_in,
                              void* d_out, int out_size, void* d_ws, size_t ws_size,
                              hipStream_t stream)
{
    const float* points  = (const float*)d_in[0];
    const float* p1_w0   = (const float*)d_in[1];
    const float* p1_b0   = (const float*)d_in[2];
    const float* p1_g0   = (const float*)d_in[3];
    const float* p1_bt0  = (const float*)d_in[4];
    const float* p1_w1   = (const float*)d_in[5];
    const float* p1_b1   = (const float*)d_in[6];
    const float* p1_g1   = (const float*)d_in[7];
    const float* p1_bt1  = (const float*)d_in[8];
    const float* p2_w0   = (const float*)d_in[9];
    const float* p2_b0   = (const float*)d_in[10];
    const float* p2_g0   = (const float*)d_in[11];
    const float* p2_bt0  = (const float*)d_in[12];
    const float* p2_w1   = (const float*)d_in[13];
    const float* p2_b1   = (const float*)d_in[14];
    const float* p2_g1   = (const float*)d_in[15];
    const float* p2_bt1  = (const float*)d_in[16];
    float* out = (float*)d_out;

    float* ws = (float*)d_ws;
    int*      idx     = (int*)ws;                    // 655360
    float*    sums1p  = ws + 655360;                 // 64*4*27  = 6912   (zero)
    float*    sums2p  = sums1p + 6912;               // 64*4*8*2 = 4096   (zero)
    float*    sumsAp  = sums2p + 4096;               // 16*4*8*2 = 1024   (zero)
    float*    sumsBp  = sumsAp + 1024;               // 1024              (zero)
    unsigned* maxenc  = (unsigned*)(sumsBp + 1024);  // 5120              (zero)
    unsigned* minenc  = maxenc + 5120;               // 5120              (0xFF)
    float*    s1      = (float*)(minenc + 5120);     // 128
    float*    t1      = s1 + 128;                    // 128
    float*    m1      = t1 + 128;                    // 5120
    float*    yp2a    = m1 + 5120;                   // 40960
    float*    zp2a    = yp2a + 40960;                // 40960
    float*    yp2b    = zp2a + 40960;                // 81920

    // zero accumulators (sums1p..maxenc contiguous), set minenc to 0xFF
    hipMemsetAsync(sums1p, 0, (6912 + 4096 + 1024 + 1024 + 5120) * sizeof(float), stream);
    hipMemsetAsync(minenc, 0xFF, 5120 * sizeof(unsigned), stream);

    knn_kernel<<<512, 512, 0, stream>>>(points, idx);
    moments_x_kernel<<<2560, 256, 0, stream>>>(points, idx, sums1p);
    finalize1_kernel<<<1, 128, 0, stream>>>(sums1p, p1_w0, p1_b0, p1_g0, p1_bt0, s1, t1);
    fused_main_kernel<<<10240, 256, 0, stream>>>(points, idx, p1_w0, s1, t1, p1_w1, p1_b1,
                                                 sums2p, maxenc, minenc);
    build_m1_kernel<<<20, 256, 0, stream>>>(sums2p, maxenc, minenc, p1_g1, p1_bt1, m1);
    p2_gemm_kernel<64, 16><<<160, 256, 0, stream>>>(m1, p2_w0, p2_b0, yp2a, sumsAp, 64);
    p2_finalize_kernel<16><<<160, 256, 0, stream>>>(yp2a, sumsAp, p2_g0, p2_bt0, zp2a, 64, 1280.0f);
    p2_gemm_kernel<512, 16><<<320, 256, 0, stream>>>(zp2a, p2_w1, p2_b1, yp2b, sumsBp, 128);
    p2_finalize_kernel<16><<<320, 256, 0, stream>>>(yp2b, sumsBp, p2_g1, p2_bt1, out, 128, 2560.0f);
}

// Round 2
// 423.095 us; speedup vs baseline: 1.6892x; 1.6892x over previous
//
#include <hip/hip_runtime.h>
#include <math.h>

#define NPTS   8192
#define BATCH  4
#define KNN    20
#define NKTOT  (NPTS*KNN)        // 163840 spatial positions per batch
#define EPS    1e-5f
#define TILE2  2048              // knn point tile (32KB LDS as float4)

__device__ __forceinline__ float elu(float x) { return x > 0.0f ? x : expm1f(x); }

// monotone float <-> unsigned encoding for atomic max/min on floats
__device__ __forceinline__ unsigned fenc(float f) {
    unsigned b = __float_as_uint(f);
    return b ^ ((unsigned)(((int)b) >> 31) | 0x80000000u);
}
__device__ __forceinline__ float fdec(unsigned u) {
    unsigned b = (u & 0x80000000u) ? (u ^ 0x80000000u) : ~u;
    return __uint_as_float(b);
}

// ---------------------------------------------------------------------------
// K0: pack points into (x,y,z,-0.5*|p|^2) so knn score s = q.p + w gives
// dist = |q|^2 - 2s (ordering by s is exactly ordering by dist).
// ---------------------------------------------------------------------------
__global__ __launch_bounds__(256) void prep_kernel(const float* __restrict__ points,
                                                   float4* __restrict__ pts4)
{
    const int t = blockIdx.x * 256 + threadIdx.x;     // 32768
    const int b = t >> 13, n = t & (NPTS - 1);
    const float* px = points + b * 3 * NPTS;
    float x = px[n], y = px[NPTS + n], z = px[2 * NPTS + n];
    pts4[t] = make_float4(x, y, z, -0.5f * (x * x + y * y + z * z));
}

// ---------------------------------------------------------------------------
// K1: exact KNN, two-pass. One wave handles 8 queries; pass 1 computes a
// provable lower bound on the 20th-best score via per-lane maxima + bitonic
// sort; pass 2 does gated stable distributed insertion (~22 events/query).
// grid: 1024 blocks x 256 threads (4 waves/block, 32 queries/block)
// ---------------------------------------------------------------------------
__global__ __launch_bounds__(256, 4) void knn_kernel(const float4* __restrict__ pts4,
                                                     int* __restrict__ idx_out)
{
    __shared__ __align__(16) float4 tileS[TILE2];
    const int tid  = threadIdx.x;
    const int lane = tid & 63;
    const int wv   = tid >> 6;
    const int b    = blockIdx.x >> 8;                 // 256 blocks per batch
    const int q0   = (blockIdx.x & 255) * 32 + wv * 8;
    const float4* pb = pts4 + b * NPTS;

    float qx[8], qy[8], qz[8], smax[8];
#pragma unroll
    for (int q = 0; q < 8; ++q) {
        float4 qp = pb[q0 + q];
        qx[q] = qp.x; qy[q] = qp.y; qz[q] = qp.z;
        smax[q] = -INFINITY;
    }

    // ---- pass 1: per-lane max score over this lane's 128 candidates ----
    for (int t = 0; t < NPTS / TILE2; ++t) {
        __syncthreads();
        for (int i = tid; i < TILE2; i += 256) tileS[i] = pb[t * TILE2 + i];
        __syncthreads();
#pragma unroll 2
        for (int s = 0; s < TILE2 / 64; ++s) {
            float4 p = tileS[s * 64 + lane];
#pragma unroll
            for (int q = 0; q < 8; ++q) {
                float sv = fmaf(qx[q], p.x, fmaf(qy[q], p.y, fmaf(qz[q], p.z, p.w)));
                smax[q] = fmaxf(smax[q], sv);
            }
        }
    }

    // ---- bitonic sort lane maxima (ascending); rank-44 = 20th largest ----
    float sgate[8];
#pragma unroll
    for (int q = 0; q < 8; ++q) {
        float v = smax[q];
#pragma unroll
        for (int k = 2; k <= 64; k <<= 1)
#pragma unroll
            for (int j = k >> 1; j >= 1; j >>= 1) {
                float o = __shfl_xor(v, j);
                bool up = ((lane & k) == 0);
                bool keepmin = (((lane & j) == 0) == up);
                v = keepmin ? fminf(v, o) : fmaxf(v, o);
            }
        float m = __shfl(v, 44);                      // lower bound on true 20th-best s
        sgate[q] = m - 1e-4f - 1e-5f * fabsf(m);      // margin vs fp recompute jitter
    }

    // ---- pass 2: gated stable distributed insertion (lanes 0..19 = list) ----
    float mys[8]; int myi[8]; float scur[8];
#pragma unroll
    for (int q = 0; q < 8; ++q) { mys[q] = -INFINITY; myi[q] = -1; scur[q] = -INFINITY; }

    for (int t = 0; t < NPTS / TILE2; ++t) {
        __syncthreads();
        for (int i = tid; i < TILE2; i += 256) tileS[i] = pb[t * TILE2 + i];
        __syncthreads();
        for (int s = 0; s < TILE2 / 64; ++s) {
            float4 p = tileS[s * 64 + lane];
            const int jj = t * TILE2 + s * 64 + lane;
            float sv[8];
#pragma unroll
            for (int q = 0; q < 8; ++q)
                sv[q] = fmaf(qx[q], p.x, fmaf(qy[q], p.y, fmaf(qz[q], p.z, p.w)));
#pragma unroll
            for (int q = 0; q < 8; ++q) {
                unsigned long long bal = __ballot((sv[q] >= sgate[q]) & (sv[q] > scur[q]));
                while (bal) {
                    int src = __ffsll(bal) - 1;
                    bal &= bal - 1;
                    float vs = __shfl(sv[q], src);
                    int   vi = __shfl(jj, src);
                    if (vs > scur[q]) {               // re-check vs updated 20th-best
                        int   sh = (mys[q] < vs) ? 1 : 0;   // strictly worse entries shift
                        float pd = __shfl_up(mys[q], 1);
                        int   pi = __shfl_up(myi[q], 1);
                        int   ps = __shfl_up(sh, 1);
                        bool pshift = (lane > 0) && (ps != 0);
                        mys[q] = sh ? (pshift ? pd : vs) : mys[q];
                        myi[q] = sh ? (pshift ? pi : vi) : myi[q];
                        scur[q] = __shfl(mys[q], 19);
                    }
                }
            }
        }
    }

#pragma unroll
    for (int q = 0; q < 8; ++q) {
        const int qi = q0 + q;
        if (lane < KNN) idx_out[(b * NPTS + qi) * KNN + lane] = myi[q];
    }
}

// ---------------------------------------------------------------------------
// K2: accumulate per-batch x0 moments: 6 sums + 21 upper-tri products.
// grid: 2560 x 256  (one thread per (b,n,k) position)
// ---------------------------------------------------------------------------
__global__ __launch_bounds__(256) void moments_x_kernel(const float* __restrict__ points,
                                                        const int* __restrict__ idx,
                                                        float* __restrict__ sums1p)
{
    const int t = blockIdx.x * 256 + threadIdx.x;
    const int b = blockIdx.x / 640;                 // 640 blocks per batch
    const int r = t - b * NKTOT;
    const int n = r / KNN;
    const float* px = points + b * 3 * NPTS;
    const int j = idx[t];
    float cx = px[n], cy = px[NPTS + n], cz = px[2 * NPTS + n];
    float v[27];
    v[0] = cx; v[1] = cy; v[2] = cz;
    v[3] = px[j] - cx; v[4] = px[NPTS + j] - cy; v[5] = px[2 * NPTS + j] - cz;
    int p = 6;
#pragma unroll
    for (int d = 0; d < 6; ++d)
#pragma unroll
        for (int e = d; e < 6; ++e) v[p++] = v[d] * v[e];
#pragma unroll
    for (int i = 0; i < 27; ++i)
        for (int o = 32; o > 0; o >>= 1) v[i] += __shfl_xor(v[i], o);

    __shared__ float red[4][27];
    const int lane = threadIdx.x & 63, w = threadIdx.x >> 6;
    if (lane == 0)
#pragma unroll
        for (int i = 0; i < 27; ++i) red[w][i] = v[i];
    __syncthreads();
    if (threadIdx.x < 27) {
        float acc = red[0][threadIdx.x] + red[1][threadIdx.x] + red[2][threadIdx.x] + red[3][threadIdx.x];
        int slot = blockIdx.x & 63;
        atomicAdd(&sums1p[(slot * BATCH + b) * 27 + threadIdx.x], acc);
    }
}

// ---------------------------------------------------------------------------
// K3: finalize GN1 stats -> per-channel affine s1,t1.  1 block x 128 threads
// ---------------------------------------------------------------------------
__global__ void finalize1_kernel(const float* __restrict__ sums1p,
                                 const float* __restrict__ w1, const float* __restrict__ b1,
                                 const float* __restrict__ g1, const float* __restrict__ beta1,
                                 float* __restrict__ s1, float* __restrict__ t1)
{
    __shared__ float S[BATCH][27];
    const int t = threadIdx.x;
    if (t < 108) {
        int b = t / 27, i = t % 27;
        float acc = 0.f;
        for (int s = 0; s < 64; ++s) acc += sums1p[(s * BATCH + b) * 27 + i];
        S[b][i] = acc;
    }
    __syncthreads();
    const int b = t >> 5, c = t & 31;
    const float invS = 1.0f / (float)NKTOT;
    float Ex[6], M[6][6];
#pragma unroll
    for (int d = 0; d < 6; ++d) Ex[d] = S[b][d] * invS;
    int p = 6;
#pragma unroll
    for (int d = 0; d < 6; ++d)
#pragma unroll
        for (int e = d; e < 6; ++e) { float v = S[b][p++] * invS; M[d][e] = v; M[e][d] = v; }
    const int g = c >> 2;
    float msum = 0.f, qsum = 0.f;
    for (int cc = g * 4; cc < g * 4 + 4; ++cc) {
        float w[6];
#pragma unroll
        for (int d = 0; d < 6; ++d) w[d] = w1[cc * 6 + d];
        float dotEx = 0.f;
#pragma unroll
        for (int d = 0; d < 6; ++d) dotEx += w[d] * Ex[d];
        float Ey = dotEx + b1[cc];
        float Ey2 = 0.f;
#pragma unroll
        for (int d = 0; d < 6; ++d)
#pragma unroll
            for (int e = 0; e < 6; ++e) Ey2 += w[d] * w[e] * M[d][e];
        Ey2 += 2.0f * b1[cc] * dotEx + b1[cc] * b1[cc];
        msum += Ey; qsum += Ey2;
    }
    float m = msum * 0.25f;
    float var = qsum * 0.25f - m * m;
    float inv = rsqrtf(var + EPS);
    s1[b * 32 + c] = g1[c] * inv;
    t1[b * 32 + c] = g1[c] * inv * (b1[c] - m) + beta1[c];
}

// ---------------------------------------------------------------------------
// K4: fused main pass: z1 tile (LDS) -> y2 GEMM (reg-tiled) -> GN2 stats +
// per-(b,c,k) max/min over n via encoded atomics.
// grid: 4*20*128 = 10240 blocks x 256 threads. Block covers 64 n's at fixed k.
// ---------------------------------------------------------------------------
__global__ __launch_bounds__(256) void fused_main_kernel(
    const float* __restrict__ points, const int* __restrict__ idxb,
    const float* __restrict__ w1, const float* __restrict__ s1a, const float* __restrict__ t1a,
    const float* __restrict__ w2, const float* __restrict__ b2,
    float* __restrict__ sums2p, unsigned int* __restrict__ maxenc, unsigned int* __restrict__ minenc)
{
    __shared__ __align__(16) float w2t[32 * 68];   // W2^T, padded stride 68
    __shared__ __align__(16) float z1s[32 * 64];
    __shared__ float w1s[192];
    __shared__ float s1s[32], t1s[32], b2s[64];

    const int t = threadIdx.x;
    const int blk = blockIdx.x;
    const int nchunk = blk & 127;
    const int k = (blk >> 7) % 20;
    const int b = blk / (128 * 20);

    for (int i = t; i < 2048; i += 256) { int c = i >> 5, kk = i & 31; w2t[kk * 68 + c] = w2[i]; }
    if (t < 192) w1s[t] = w1[t];
    if (t < 32) { s1s[t] = s1a[b * 32 + t]; t1s[t] = t1a[b * 32 + t]; }
    if (t < 64) b2s[t] = b2[t];

    const int p = t & 63;
    const int cg = t >> 6;
    const int n = nchunk * 64 + p;
    const float* px = points + b * 3 * NPTS;
    const int j = idxb[(b * NPTS + n) * KNN + k];
    const float cx = px[n], cy = px[NPTS + n], cz = px[2 * NPTS + n];
    float x0[6];
    x0[0] = cx; x0[1] = cy; x0[2] = cz;
    x0[3] = px[j] - cx; x0[4] = px[NPTS + j] - cy; x0[5] = px[2 * NPTS + j] - cz;
    __syncthreads();
#pragma unroll
    for (int jj = 0; jj < 8; ++jj) {
        int c = cg * 8 + jj;
        float acc = 0.f;
#pragma unroll
        for (int d = 0; d < 6; ++d) acc += w1s[c * 6 + d] * x0[d];
        z1s[c * 64 + p] = elu(s1s[c] * acc + t1s[c]);
    }
    __syncthreads();

    const int pos0 = (t & 15) * 4;
    const int c0 = (t >> 4) * 4;
    float acc[4][4];
#pragma unroll
    for (int ci = 0; ci < 4; ++ci) {
        float bb = b2s[c0 + ci];
#pragma unroll
        for (int pj = 0; pj < 4; ++pj) acc[ci][pj] = bb;
    }
#pragma unroll
    for (int kk = 0; kk < 32; ++kk) {
        float4 av = *(const float4*)&w2t[kk * 68 + c0];
        float4 bv = *(const float4*)&z1s[kk * 64 + pos0];
        float avv[4] = { av.x, av.y, av.z, av.w };
        float bvv[4] = { bv.x, bv.y, bv.z, bv.w };
#pragma unroll
        for (int ci = 0; ci < 4; ++ci)
#pragma unroll
            for (int pj = 0; pj < 4; ++pj) acc[ci][pj] += avv[ci] * bvv[pj];
    }

    float ssum = 0.f, ssq = 0.f;
    float mx[4], mn[4];
#pragma unroll
    for (int ci = 0; ci < 4; ++ci) {
        float cmx = -INFINITY, cmn = INFINITY;
#pragma unroll
        for (int pj = 0; pj < 4; ++pj) {
            float v = acc[ci][pj];
            ssum += v; ssq += v * v;
            cmx = fmaxf(cmx, v); cmn = fminf(cmn, v);
        }
        mx[ci] = cmx; mn[ci] = cmn;
    }
#pragma unroll
    for (int o = 1; o < 16; o <<= 1) {
        ssum += __shfl_xor(ssum, o);
        ssq  += __shfl_xor(ssq, o);
#pragma unroll
        for (int ci = 0; ci < 4; ++ci) {
            mx[ci] = fmaxf(mx[ci], __shfl_xor(mx[ci], o));
            mn[ci] = fminf(mn[ci], __shfl_xor(mn[ci], o));
        }
    }
    if ((t & 15) == 0) {
        int g = c0 >> 3, slot = blk & 63;
        atomicAdd(&sums2p[((slot * BATCH + b) * 8 + g) * 2 + 0], ssum);
        atomicAdd(&sums2p[((slot * BATCH + b) * 8 + g) * 2 + 1], ssq);
#pragma unroll
        for (int ci = 0; ci < 4; ++ci) {
            int c = c0 + ci;
            atomicMax(&maxenc[(b * 64 + c) * KNN + k], fenc(mx[ci]));
            atomicMin(&minenc[(b * 64 + c) * KNN + k], fenc(mn[ci]));
        }
    }
}

// ---------------------------------------------------------------------------
// K5: build m1[b,c,k] = ELU(GN2-affine applied to max-or-min over n of y2)
// ---------------------------------------------------------------------------
__global__ void build_m1_kernel(const float* __restrict__ sums2p,
                                const unsigned int* __restrict__ maxenc,
                                const unsigned int* __restrict__ minenc,
                                const float* __restrict__ gamma, const float* __restrict__ beta,
                                float* __restrict__ m1)
{
    const int t = blockIdx.x * 256 + threadIdx.x;   // (b*64+c)*20+k
    const int b = t / 1280;
    const int r = t - b * 1280;
    const int c = r / 20;
    const int g = c >> 3;
    float s = 0.f, q = 0.f;
    for (int sl = 0; sl < 64; ++sl) {
        s += sums2p[((sl * BATCH + b) * 8 + g) * 2 + 0];
        q += sums2p[((sl * BATCH + b) * 8 + g) * 2 + 1];
    }
    const float cnt = 8.0f * (float)NKTOT;
    float m = s / cnt;
    float var = q / cnt - m * m;
    float inv = rsqrtf(var + EPS);
    float sc = gamma[c] * inv;
    float tt = beta[c] - sc * m;
    float y = (sc >= 0.f) ? fdec(maxenc[t]) : fdec(minenc[t]);
    m1[t] = elu(sc * y + tt);
}

// ---------------------------------------------------------------------------
// K6/K8: pointwise conv (CIN -> COUT over K=20) + raw output + GN stat partials
// ---------------------------------------------------------------------------
template <int CIN, int SLOTS>
__global__ void p2_gemm_kernel(const float* __restrict__ zin, const float* __restrict__ w,
                               const float* __restrict__ bias, float* __restrict__ yout,
                               float* __restrict__ sumsp, int chans_per_group)
{
    const int t = blockIdx.x * 256 + threadIdx.x;
    const int per_b = (gridDim.x * 256) / BATCH;
    const int b = t / per_b;
    const int r = t - b * per_b;
    const int o = r / 20;
    const int k = r - o * 20;
    const float* zb = zin + b * CIN * 20;
    const float* wrow = w + o * CIN;
    float acc = bias[o];
    for (int c = 0; c < CIN; c += 4) {
        float4 wv = *(const float4*)&wrow[c];
        acc += wv.x * zb[(c + 0) * 20 + k] + wv.y * zb[(c + 1) * 20 + k]
             + wv.z * zb[(c + 2) * 20 + k] + wv.w * zb[(c + 3) * 20 + k];
    }
    yout[t] = acc;

    __shared__ float ls[16];
    if (threadIdx.x < 16) ls[threadIdx.x] = 0.f;
    __syncthreads();
    const int g = o / chans_per_group;
    atomicAdd(&ls[g * 2 + 0], acc);
    atomicAdd(&ls[g * 2 + 1], acc * acc);
    __syncthreads();
    if (threadIdx.x < 16) {
        int slot = blockIdx.x & (SLOTS - 1);
        atomicAdd(&sumsp[(slot * BATCH + b) * 16 + threadIdx.x], ls[threadIdx.x]);
    }
}

// K7/K9: apply GN affine + ELU using partial sums
template <int SLOTS>
__global__ void p2_finalize_kernel(const float* __restrict__ y, const float* __restrict__ sumsp,
                                   const float* __restrict__ gamma, const float* __restrict__ beta,
                                   float* __restrict__ z, int chans_per_group, float cnt)
{
    const int t = blockIdx.x * 256 + threadIdx.x;
    const int per_b = (gridDim.x * 256) / BATCH;
    const int b = t / per_b;
    const int r = t - b * per_b;
    const int o = r / 20;
    const int g = o / chans_per_group;
    float s = 0.f, q = 0.f;
    for (int sl = 0; sl < SLOTS; ++sl) {
        s += sumsp[(sl * BATCH + b) * 16 + g * 2 + 0];
        q += sumsp[(sl * BATCH + b) * 16 + g * 2 + 1];
    }
    float m = s / cnt;
    float var = q / cnt - m * m;
    float inv = rsqrtf(var + EPS);
    float v = gamma[o] * inv * (y[t] - m) + beta[o];
    z[t] = elu(v);
}

// ---------------------------------------------------------------------------
extern "C" void kernel_launch(void* const* d_in, const int* in_sizes, int n_in,
                              void* d_out, int out_size, void* d_ws, size_t ws_size,
                              hipStream_t stream)
{
    const float* points  = (const float*)d_in[0];
    const float* p1_w0   = (const float*)d_in[1];
    const float* p1_b0   = (const float*)d_in[2];
    const float* p1_g0   = (const float*)d_in[3];
    const float* p1_bt0  = (const float*)d_in[4];
    const float* p1_w1   = (const float*)d_in[5];
    const float* p1_b1   = (const float*)d_in[6];
    const float* p1_g1   = (const float*)d_in[7];
    const float* p1_bt1  = (const float*)d_in[8];
    const float* p2_w0   = (const float*)d_in[9];
    const float* p2_b0   = (const float*)d_in[10];
    const float* p2_g0   = (const float*)d_in[11];
    const float* p2_bt0  = (const float*)d_in[12];
    const float* p2_w1   = (const float*)d_in[13];
    const float* p2_b1   = (const float*)d_in[14];
    const float* p2_g1   = (const float*)d_in[15];
    const float* p2_bt1  = (const float*)d_in[16];
    float* out = (float*)d_out;

    float* ws = (float*)d_ws;
    int*      idx     = (int*)ws;                    // 655360
    float*    sums1p  = ws + 655360;                 // 64*4*27  = 6912   (zero)
    float*    sums2p  = sums1p + 6912;               // 64*4*8*2 = 4096   (zero)
    float*    sumsAp  = sums2p + 4096;               // 1024              (zero)
    float*    sumsBp  = sumsAp + 1024;               // 1024              (zero)
    unsigned* maxenc  = (unsigned*)(sumsBp + 1024);  // 5120              (zero)
    unsigned* minenc  = maxenc + 5120;               // 5120              (0xFF)
    float*    s1      = (float*)(minenc + 5120);     // 128
    float*    t1      = s1 + 128;                    // 128
    float*    m1      = t1 + 128;                    // 5120
    float*    yp2a    = m1 + 5120;                   // 40960
    float*    zp2a    = yp2a + 40960;                // 40960
    float*    yp2b    = zp2a + 40960;                // 81920
    // pts4 (32768 float4 = 131072 floats) aliases yp2a..yp2b head: only live
    // between prep_kernel and knn_kernel, before yp2a/zp2a/yp2b are written.
    float4*   pts4    = (float4*)yp2a;

    hipMemsetAsync(sums1p, 0, (6912 + 4096 + 1024 + 1024 + 5120) * sizeof(float), stream);
    hipMemsetAsync(minenc, 0xFF, 5120 * sizeof(unsigned), stream);

    prep_kernel<<<128, 256, 0, stream>>>(points, pts4);
    knn_kernel<<<1024, 256, 0, stream>>>(pts4, idx);
    moments_x_kernel<<<2560, 256, 0, stream>>>(points, idx, sums1p);
    finalize1_kernel<<<1, 128, 0, stream>>>(sums1p, p1_w0, p1_b0, p1_g0, p1_bt0, s1, t1);
    fused_main_kernel<<<10240, 256, 0, stream>>>(points, idx, p1_w0, s1, t1, p1_w1, p1_b1,
                                                 sums2p, maxenc, minenc);
    build_m1_kernel<<<20, 256, 0, stream>>>(sums2p, maxenc, minenc, p1_g1, p1_bt1, m1);
    p2_gemm_kernel<64, 16><<<160, 256, 0, stream>>>(m1, p2_w0, p2_b0, yp2a, sumsAp, 64);
    p2_finalize_kernel<16><<<160, 256, 0, stream>>>(yp2a, sumsAp, p2_g0, p2_bt0, zp2a, 64, 1280.0f);
    p2_gemm_kernel<512, 16><<<320, 256, 0, stream>>>(zp2a, p2_w1, p2_b1, yp2b, sumsBp, 128);
    p2_finalize_kernel<16><<<320, 256, 0, stream>>>(yp2b, sumsBp, p2_g1, p2_bt1, out, 128, 2560.0f);
}